// Round 19
// baseline (405.776 us; speedup 1.0000x reference)
//
#include <hip/hip_runtime.h>

typedef unsigned short ushort_t;
typedef short short8 __attribute__((ext_vector_type(8)));
typedef float f32x4 __attribute__((ext_vector_type(4)));

// problem constants
#define NN   2048     // nodes
#define EE   8192     // edges
#define CC   128      // channels
#define HCC  512      // H*C
#define DFF  2048
#define QB   512      // query rows per quarter (fallback path)

#define BM 128
#define BN 128
#define BKK 64

enum { EPI_STORE_BIAS = 0, EPI_EXP = 1, EPI_GELU = 2, EPI_ATOMIC = 3 };

__device__ __forceinline__ float b2f(ushort_t u) {
    return __uint_as_float(((unsigned int)u) << 16);
}
__device__ __forceinline__ ushort_t f2b(float f) {
    unsigned int u = __float_as_uint(f);
    u += 0x7fffu + ((u >> 16) & 1u);   // round-to-nearest-even
    return (ushort_t)(u >> 16);
}

#define GLOAD16(gp, lp)                                                        \
    __builtin_amdgcn_global_load_lds(                                          \
        (const __attribute__((address_space(1))) unsigned int*)(gp),           \
        (__attribute__((address_space(3))) unsigned int*)(lp), 16, 0, 0)

// ---------------------------------------------------------------------------
__global__ void probe_k(const void* __restrict__ x, const void* __restrict__ idx,
                        int* __restrict__ flags)
{
    if (threadIdx.x == 0 && blockIdx.x == 0) {
        const ushort_t* xu = (const ushort_t*)x;
        float mx = 0.f;
        for (int i = 0; i < 512; i++) {
            float v = fabsf(b2f(xu[i]));
            if (v < 1e30f) mx = fmaxf(mx, v);
            else mx = 1e30f;
        }
        flags[0] = (mx > 1e4f) ? 1 : 0;
        const int* ii = (const int*)idx;
        int allz = 1;
        for (int j = 1; j < 16; j += 2)
            if (ii[j] != 0) allz = 0;
        flags[1] = allz;
    }
}

__global__ void cvt_idx(const void* __restrict__ in, int* __restrict__ out,
                        const int* __restrict__ flags)
{
    int i = blockIdx.x * 256 + threadIdx.x;
    if (i < EE)
        out[i] = flags[1] ? (int)((const long long*)in)[i] : ((const int*)in)[i];
}

// ---------------------------------------------------------------------------
// Counting sort of edges by target; emits sorted_e, seg_off.
// ---------------------------------------------------------------------------
__global__ __launch_bounds__(256)
void sort_edges(const int* __restrict__ idx, int* __restrict__ sorted_e,
                int* __restrict__ seg_off)
{
    __shared__ int hist[NN];
    __shared__ int cursor[NN];
    __shared__ float wsum[4];
    const int tid = threadIdx.x;
    for (int i = tid; i < NN; i += 256) hist[i] = 0;
    __syncthreads();
    for (int e = tid; e < EE; e += 256) atomicAdd(&hist[idx[e]], 1);
    __syncthreads();
    int s = 0;
#pragma unroll
    for (int j = 0; j < 8; j++) s += hist[tid * 8 + j];
    int lane = tid & 63, w = tid >> 6;
    int sc = s;
#pragma unroll
    for (int o = 1; o < 64; o <<= 1) {
        int t = __shfl_up(sc, o, 64);
        if (lane >= o) sc += t;
    }
    if (lane == 63) wsum[w] = (float)sc;
    __syncthreads();
    int wbase = 0;
    for (int j = 0; j < 4; j++) if (j < w) wbase += (int)wsum[j];
    int excl = wbase + sc - s;
    int run = excl;
#pragma unroll
    for (int j = 0; j < 8; j++) {
        int b = tid * 8 + j;
        cursor[b] = run;
        seg_off[b] = run;
        run += hist[b];
    }
    if (tid == 0) seg_off[NN] = EE;
    __syncthreads();
    for (int e = tid; e < EE; e += 256) {
        int t = idx[e];
        int pos = atomicAdd(&cursor[t], 1);
        sorted_e[pos] = e;
    }
}

__global__ void cvt_x(const void* __restrict__ in, ushort_t* __restrict__ xb,
                      float* __restrict__ xf, const int* __restrict__ flags)
{
    long i = (long)blockIdx.x * 256 + threadIdx.x;   // NN*CC
    float v = flags[0] ? ((const float*)in)[i] : b2f(((const ushort_t*)in)[i]);
    xf[i] = v;
    xb[i] = f2b(v);
}

__global__ void cvt_vecs(const void* bq, const void* bk, const void* bv,
                         const void* bz, const void* lnw, const void* lnb,
                         const void* b3, const void* b1, const void* b2,
                         float* __restrict__ out, const int* __restrict__ flags)
{
    int i = blockIdx.x * 256 + threadIdx.x;
    if (i >= 6144) return;
    const void* src; int o;
    if      (i < 512)  { src = bq;  o = i; }
    else if (i < 1024) { src = bk;  o = i - 512; }
    else if (i < 1536) { src = bv;  o = i - 1024; }
    else if (i < 1664) { src = bz;  o = i - 1536; }
    else if (i < 1792) { src = lnw; o = i - 1664; }
    else if (i < 1920) { src = lnb; o = i - 1792; }
    else if (i < 2048) { src = b3;  o = i - 1920; }
    else if (i < 4096) { src = b1;  o = i - 2048; }
    else               { src = b2;  o = i - 4096; }
    out[i] = flags[0] ? ((const float*)src)[o] : b2f(((const ushort_t*)src)[o]);
}

__global__ void transpose_cvt(const void* __restrict__ in, ushort_t* __restrict__ out,
                              int R, int C, const int* __restrict__ flags)
{
    __shared__ ushort_t t[32][33];
    const int f  = flags[0];
    const int bx = blockIdx.x * 32;
    const int by = blockIdx.y * 32;
    const int tx = threadIdx.x, ty = threadIdx.y;
#pragma unroll
    for (int i = 0; i < 32; i += 8) {
        long src = (long)(by + ty + i) * C + bx + tx;
        t[ty + i][tx] = f ? f2b(((const float*)in)[src]) : ((const ushort_t*)in)[src];
    }
    __syncthreads();
#pragma unroll
    for (int i = 0; i < 32; i += 8)
        out[(long)(bx + ty + i) * R + by + tx] = t[tx][ty + i];
}

__global__ void transpose_qkv(const void* q, const void* k, const void* v,
                              ushort_t* __restrict__ out, const int* __restrict__ flags)
{
    __shared__ ushort_t t[32][33];
    const void* in = blockIdx.z == 0 ? q : (blockIdx.z == 1 ? k : v);
    const int f  = flags[0];
    const int bx = blockIdx.x * 32;
    const int by = blockIdx.y * 32;
    const int tx = threadIdx.x, ty = threadIdx.y;
#pragma unroll
    for (int i = 0; i < 32; i += 8) {
        long src = (long)(by + ty + i) * HCC + bx + tx;
        t[ty + i][tx] = f ? f2b(((const float*)in)[src]) : ((const ushort_t*)in)[src];
    }
    __syncthreads();
#pragma unroll
    for (int i = 0; i < 32; i += 8)
        out[(size_t)blockIdx.z * HCC * CC + (long)(bx + ty + i) * CC + by + tx]
            = t[tx][ty + i];
}

__global__ __launch_bounds__(256)
void gather_k(const ushort_t* __restrict__ KM, ushort_t* __restrict__ Ksort,
              const int* __restrict__ sorted_e)
{
    const size_t hb = (size_t)blockIdx.z * EE * CC;
    const int j  = blockIdx.x * 16 + (threadIdx.x >> 4);
    const int l8 = (threadIdx.x & 15) * 8;
    const int e  = sorted_e[j];
    *(short8*)(Ksort + hb + (size_t)j * CC + l8) =
        *(const short8*)(KM + hb + (size_t)e * CC + l8);
}

__global__ void transpose_v(const ushort_t* __restrict__ VM, ushort_t* __restrict__ VT,
                            const int* __restrict__ sorted_e)
{
    __shared__ ushort_t t[32][33];
    const ushort_t* in = VM + (size_t)blockIdx.z * EE * CC;
    ushort_t* out      = VT + (size_t)blockIdx.z * EE * CC;
    const int bx = blockIdx.x * 32;
    const int by = blockIdx.y * 32;
    const int tx = threadIdx.x, ty = threadIdx.y;
#pragma unroll
    for (int i = 0; i < 32; i += 8) {
        const long rg = sorted_e[by + ty + i];
        t[ty + i][tx] = in[rg * CC + bx + tx];
    }
    __syncthreads();
#pragma unroll
    for (int i = 0; i < 32; i += 8)
        out[(long)(bx + ty + i) * EE + by + tx] = t[tx][ty + i];
}

// ---------------------------------------------------------------------------
// Unified NT GEMM. MODE 0: bz = split-K. MODE 1: bz = head. MODE 2: by =
// head, bz = split-K. Strides aHS/bHS/biasHS in elements, cHS in BYTES.
// T2 LDS XOR-swizzle on staging (r11: conflicts 6.29M -> 0).
// T1 XCD bijective block swizzle (r12: FETCH -45%).
// r13: non-atomic epilogues LDS-stage the C tile, coalesced short8 stores.
// r17: 2-phase double-buffered prefetch (pays on large-kchunk dispatches,
// e.g. single-dispatch W2 with 32 K-iters; r18: -39us total).
// ---------------------------------------------------------------------------
template <int EPI, bool GATHER, int MODE>
__global__ __launch_bounds__(256, 2)
void gemm_h(const ushort_t* __restrict__ A, long lda, long aHS,
            const ushort_t* __restrict__ B, long ldb, long bHS,
            const int* __restrict__ gidx,
            const float* __restrict__ bias, long biasHS,
            void* __restrict__ Cp, long ldc, long cHS,
            int kchunk, float alpha)
{
    constexpr int TSZ = BM * BKK + BN * BKK;          // 16384 elems = 32 KB
    __shared__ __align__(16) ushort_t smem[2 * TSZ];  // double buffer, 64 KB

    const int tid  = threadIdx.x;
    const int lane = tid & 63;
    const int wave = tid >> 6;

    // ---- T1: bijective XCD swizzle over the flattened grid ----
    const int gx = gridDim.x, gy = gridDim.y;
    const int nwg = gx * gy * gridDim.z;
    const int bid = blockIdx.x + gx * (blockIdx.y + gy * blockIdx.z);
    const int q8 = nwg >> 3, r8 = nwg & 7;
    const int xcd = bid & 7, slot = bid >> 3;
    const int nb = (xcd < r8) ? (xcd * (q8 + 1) + slot) : (r8 + xcd * q8 + slot);
    const int bxi = nb % gx;
    const int tq  = nb / gx;
    const int byi = tq % gy;
    const int bzi = tq / gy;

    const long bm = (long)bxi * BM;

    long bn; int head, k0;
    if (MODE == 1)      { head = bzi; k0 = 0;               bn = (long)byi * BN; }
    else if (MODE == 2) { head = byi; k0 = bzi * kchunk;    bn = 0; }
    else                { head = 0;   k0 = bzi * kchunk;    bn = (long)byi * BN; }
    const int k1 = k0 + kchunk;

    A += (size_t)head * aHS;
    B += (size_t)head * bHS;
    const float* bp = bias + (size_t)head * biasHS;
    Cp = (void*)((char*)Cp + (size_t)head * cHS);

    const f32x4 fzero = {0.f, 0.f, 0.f, 0.f};
    f32x4 acc[4][4];
#pragma unroll
    for (int i = 0; i < 4; i++)
#pragma unroll
        for (int j = 0; j < 4; j++) acc[i][j] = fzero;

    const int arow = tid >> 3;          // 0..31
    const int acol = (((tid & 7) ^ (arow & 7)) * 8);   // T2 source swizzle

    const ushort_t* ap[4];
    const ushort_t* bpt[4];
#pragma unroll
    for (int i = 0; i < 4; i++) {
        long r  = bm + arow + i * 32;     // (arow+32i)&7 == arow&7
        long gr = GATHER ? (long)gidx[r] : r;
        ap[i]  = A + gr * lda + acol;
        bpt[i] = B + (bn + arow + i * 32) * ldb + acol;
    }
    const int t8  = tid * 8;
    const int wr  = (wave >> 1) * 64;
    const int wc  = (wave & 1) * 64;
    const int ra  = lane & 15;
    const int kgi = lane >> 4;            // 0..3 k-group
    const int r7  = lane & 7;             // row&7 of the fragment row

    // ---- prologue: stage first K-tile into buffer 0 ----
    {
        ushort_t* As0 = smem;
        ushort_t* Bs0 = smem + BM * BKK;
#pragma unroll
        for (int i = 0; i < 4; i++) GLOAD16(ap[i] + k0, &As0[t8 + i * 2048]);
#pragma unroll
        for (int i = 0; i < 4; i++) GLOAD16(bpt[i] + k0, &Bs0[t8 + i * 2048]);
    }
    asm volatile("s_waitcnt vmcnt(0)" ::: "memory");
    __builtin_amdgcn_s_barrier();

    int cur = 0;
    for (int kt = k0; kt < k1; kt += BKK) {
        // issue NEXT tile's loads first — in flight during this compute
        if (kt + BKK < k1) {
            ushort_t* Asn = smem + (cur ^ 1) * TSZ;
            ushort_t* Bsn = Asn + BM * BKK;
#pragma unroll
            for (int i = 0; i < 4; i++)
                GLOAD16(ap[i] + kt + BKK, &Asn[t8 + i * 2048]);
#pragma unroll
            for (int i = 0; i < 4; i++)
                GLOAD16(bpt[i] + kt + BKK, &Bsn[t8 + i * 2048]);
        }
        // compute current buffer
        const ushort_t* Asc = smem + cur * TSZ;
        const ushort_t* Bsc = Asc + BM * BKK;
#pragma unroll
        for (int ks = 0; ks < 2; ks++) {
            const int cswz = (((ks * 4 + kgi) ^ r7) * 8);   // swizzled chunk
            short8 af[4], bfr[4];
#pragma unroll
            for (int mi = 0; mi < 4; mi++)
                af[mi] = *(const short8*)&Asc[(wr + mi * 16 + ra) * BKK + cswz];
#pragma unroll
            for (int ni = 0; ni < 4; ni++)
                bfr[ni] = *(const short8*)&Bsc[(wc + ni * 16 + ra) * BKK + cswz];
#pragma unroll
            for (int mi = 0; mi < 4; mi++)
#pragma unroll
                for (int ni = 0; ni < 4; ni++)
                    acc[mi][ni] = __builtin_amdgcn_mfma_f32_16x16x32_bf16(
                        af[mi], bfr[ni], acc[mi][ni], 0, 0, 0);
        }
        asm volatile("s_waitcnt vmcnt(0)" ::: "memory");
        __builtin_amdgcn_s_barrier();
        cur ^= 1;
    }

    if (EPI == EPI_ATOMIC) {
#pragma unroll
        for (int mi = 0; mi < 4; mi++) {
#pragma unroll
            for (int ni = 0; ni < 4; ni++) {
                const long row0 = bm + wr + mi * 16 + (lane >> 4) * 4;
                const long col  = bn + wc + ni * 16 + ra;
#pragma unroll
                for (int r = 0; r < 4; r++)
                    unsafeAtomicAdd(&((float*)Cp)[(row0 + r) * ldc + col],
                                    acc[mi][ni][r]);
            }
        }
    } else {
        // ---- LDS-staged coalesced C write (reuses smem as 128x128 tile) ----
        ushort_t* Cs = smem;
#pragma unroll
        for (int mi = 0; mi < 4; mi++) {
#pragma unroll
            for (int ni = 0; ni < 4; ni++) {
                const int crow0 = wr + mi * 16 + (lane >> 4) * 4;
                const int ccol  = wc + ni * 16 + ra;
#pragma unroll
                for (int r = 0; r < 4; r++) {
                    float v = acc[mi][ni][r];
                    if (EPI == EPI_STORE_BIAS) {
                        v += bp[bn + ccol];
                    } else if (EPI == EPI_EXP) {
                        v = __expf(v * alpha);
                    } else { // EPI_GELU
                        v += bp[bn + ccol];
                        v = 0.5f * v * (1.f + erff(v * 0.70710678118654752f));
                    }
                    const int crow = crow0 + r;
                    Cs[crow * BN + (ccol ^ (((crow & 7) << 3)))] = f2b(v);
                }
            }
        }
        __syncthreads();
#pragma unroll
        for (int it = 0; it < 8; it++) {
            const int idx = it * 2048 + tid * 8;
            const int row = idx >> 7;
            const int col = idx & 127;
            *(short8*)((ushort_t*)Cp + (bm + row) * ldc + bn + col) =
                *(const short8*)&Cs[row * BN + (col ^ ((row & 7) << 3))];
        }
    }
}

// ---------------------------------------------------------------------------
// Segmented softmax normalize on sorted-column P.
// r19: in-place scale during the phase-1 walk. r18 counters showed 12.07M
// conflict cycles (~20us/dispatch) from phase-2's D[sseg[e]] gather (4-way:
// 64 lanes spanning 128 consecutive D entries) plus 256MB of sseg index
// traffic. The owning thread now re-walks its ~4-element span multiplying by
// inv — walk is conflict-free by the same PH padding; phase 2 becomes a pure
// coalesced read->f2b->store with no gather and no index loads.
// ---------------------------------------------------------------------------
#define PH(e) ((e) + ((e) >> 6))
__global__ __launch_bounds__(1024)
void seg_norm_sorted(ushort_t* __restrict__ P, const int* __restrict__ seg_off)
{
    __shared__ float rowf[EE + EE / 64];   // 33.3 KB padded
    ushort_t* row = P + (long)blockIdx.x * EE;
    const int tid = threadIdx.x;
    const int e = tid * 8;

    {
        short8 v = *(const short8*)(row + e);
#pragma unroll
        for (int j = 0; j < 8; j++)
            rowf[PH(e + j)] = b2f((ushort_t)v[j]);
    }
    __syncthreads();

    {
        const int t2 = tid * 2;
        int prev = seg_off[t2];
#pragma unroll
        for (int j = 0; j < 2; j++) {
            const int e1 = seg_off[t2 + j + 1];
            float s = 0.f;
            for (int k = prev; k < e1; k++) s += rowf[PH(k)];
            const float inv = 1.f / (s + 1e-16f);
            for (int k = prev; k < e1; k++) rowf[PH(k)] *= inv;
            prev = e1;
        }
    }
    __syncthreads();

    {
        short8 o;
#pragma unroll
        for (int j = 0; j < 8; j++)
            o[j] = (short)f2b(rowf[PH(e + j)]);
        *(short8*)(row + e) = o;
    }
}

// scoreF [NN,HCC] f32 -> bf16
__global__ void cvt_sb(const float* __restrict__ in, ushort_t* __restrict__ out)
{
    long i = (long)blockIdx.x * 256 + threadIdx.x;
    out[i] = f2b(in[i]);
}

__global__ __launch_bounds__(256)
void add_bias_x_reduce(float* __restrict__ u, const float* __restrict__ bias,
                       const float* __restrict__ x, float* __restrict__ red)
{
    long i = (long)blockIdx.x * 256 + threadIdx.x;
    float v = u[i] + bias[i & (CC - 1)] + x[i];
    u[i] = v;
    float s = v, s2 = v * v;
#pragma unroll
    for (int o = 32; o > 0; o >>= 1) {
        s  += __shfl_down(s, o, 64);
        s2 += __shfl_down(s2, o, 64);
    }
    __shared__ float ps[4], ps2[4];
    int w = threadIdx.x >> 6;
    if ((threadIdx.x & 63) == 0) { ps[w] = s; ps2[w] = s2; }
    __syncthreads();
    if (threadIdx.x == 0) {
        float a = 0.f, b = 0.f;
#pragma unroll
        for (int j = 0; j < 4; j++) { a += ps[j]; b += ps2[j]; }
        unsafeAtomicAdd(&red[0], a);
        unsafeAtomicAdd(&red[1], b);
    }
}

__global__ void ln_fin_mid(const float* __restrict__ u, const float* __restrict__ red,
                           const float* __restrict__ w, const float* __restrict__ b,
                           ushort_t* __restrict__ out, float invn)
{
    long i = (long)blockIdx.x * 256 + threadIdx.x;
    float mean = red[0] * invn;
    float var  = red[1] * invn - mean * mean;
    float rs   = rsqrtf(var + 1e-5f);
    int c = (int)(i & (CC - 1));
    out[i] = f2b((u[i] - mean) * rs * w[c] + b[c]);
}

__global__ void ln_fin_out(const float* __restrict__ u, const float* __restrict__ red,
                           const float* __restrict__ w, const float* __restrict__ b,
                           void* __restrict__ out, const int* __restrict__ flags,
                           float invn)
{
    long i = (long)blockIdx.x * 256 + threadIdx.x;
    float mean = red[0] * invn;
    float var  = red[1] * invn - mean * mean;
    float rs   = rsqrtf(var + 1e-5f);
    int c = (int)(i & (CC - 1));
    float v = (u[i] - mean) * rs * w[c] + b[c];
    if (flags[0]) ((float*)out)[i] = v;
    else          ((ushort_t*)out)[i] = f2b(v);
}

// ---------------------------------------------------------------------------
extern "C" void kernel_launch(void* const* d_in, const int* in_sizes, int n_in,
                              void* d_out, int out_size, void* d_ws, size_t ws_size,
                              hipStream_t stream)
{
    const void* x_raw   = d_in[0];
    const void* idx_raw = d_in[1];
    const void* Wq = d_in[2];  const void* bq = d_in[3];
    const void* Wk = d_in[4];  const void* bk = d_in[5];
    const void* Wv = d_in[6];  const void* bv = d_in[7];
    const void* Wz = d_in[8];  const void* bz = d_in[9];
    const void* lnw = d_in[10]; const void* lnb = d_in[11];
    const void* W1 = d_in[12]; const void* b1 = d_in[13];
    const void* W2 = d_in[14]; const void* b2 = d_in[15];
    const void* W3 = d_in[16]; const void* b3 = d_in[17];

    char* ws = (char*)d_ws;
    size_t off = 0;
    auto carve = [&](size_t bytes) -> char* {
        char* p = ws + off;
        off += (bytes + 255) & ~(size_t)255;
        return p;
    };

    // ---- persistent region (~6 MB) ----
    int*      flags  = (int*)     carve(256);
    int*      idx32  = (int*)     carve((size_t)EE * 4);
    int*      sortedE= (int*)     carve((size_t)EE * 4);
    int*      segOff = (int*)     carve((size_t)(NN + 1) * 4);
    ushort_t* x_bf  = (ushort_t*)carve((size_t)NN * CC * 2);
    float*    x_f   = (float*)   carve((size_t)NN * CC * 4);
    float*    vecF  = (float*)   carve(6144 * 4);
    float*    bqF  = vecF;        float* bkF  = vecF + 512;
    float*    bzF  = vecF + 1536;
    float*    lnwF = vecF + 1664; float* lnbF = vecF + 1792;
    float*    b3F  = vecF + 1920; float* b1F  = vecF + 2048;
    float*    b2F  = vecF + 4096;
    ushort_t* wqkvT = (ushort_t*)carve((size_t)3 * HCC * CC * 2);
    ushort_t* wqT = wqkvT;
    ushort_t* wkT = wqkvT + (size_t)HCC * CC;   // wvT adjacent (bHS)
    ushort_t* wzT   = (ushort_t*)carve((size_t)CC * HCC * 2);
    ushort_t* scoreB= (ushort_t*)carve((size_t)NN * HCC * 2);
    float*    zF    = (float*)   carve((size_t)NN * CC * 4);
    ushort_t* zln   = (ushort_t*)carve((size_t)NN * CC * 2);
    float*    ffnF  = (float*)   carve((size_t)NN * CC * 4);
    float*    red   = (float*)   carve(256);

    // ---- attention scratch, overlaid by FFN scratch ----
    size_t scratch0 = off;
    ushort_t* QM    = (ushort_t*)carve((size_t)NN * HCC * 2);       // 2 MB
    ushort_t* KVM   = (ushort_t*)carve((size_t)2 * EE * HCC * 2);   // 16 MB (KM|VM)
    ushort_t* KM = KVM;
    ushort_t* VM = KVM + (size_t)EE * HCC;
    ushort_t* Ksort = (ushort_t*)carve((size_t)EE * HCC * 2);       // 8 MB
    ushort_t* VT    = (ushort_t*)carve((size_t)EE * HCC * 2);       // 8 MB
    float*    scoreF= (float*)   carve((size_t)NN * HCC * 4);       // 4 MB
    size_t pOff = off;
    // merged path: full P [4 heads][2048 rows][8192] = 128 MB
    off = pOff;
    carve((size_t)4 * NN * EE * 2);
    size_t total_attn_full = off;
    // quartered fallback: P [4 heads][512 rows][8192] = 32 MB
    size_t total_attn_quart = pOff + (((size_t)4 * QB * EE * 2 + 255) & ~(size_t)255);
    ushort_t* P = (ushort_t*)(ws + pOff);
    // FFN overlay
    off = scratch0;
    ushort_t* w1T = (ushort_t*)carve((size_t)DFF * CC * 2);
    ushort_t* w2T = (ushort_t*)carve((size_t)DFF * DFF * 2);
    ushort_t* w3T = (ushort_t*)carve((size_t)CC * DFF * 2);
    ushort_t* h1  = (ushort_t*)carve((size_t)NN * DFF * 2);
    ushort_t* h2  = (ushort_t*)carve((size_t)NN * DFF * 2);
    size_t total_ffn = off;

    const bool merged = ws_size >= (total_attn_full > total_ffn ? total_attn_full
                                                                : total_ffn);
    size_t required_attn = merged ? total_attn_full : total_attn_quart;
    size_t required = required_attn > total_ffn ? required_attn : total_ffn;
    if (ws_size < required) return;   // diagnostic: absmax ~5 => ws too small

    // ---- canonicalization + edge sort ----
    probe_k<<<1, 64, 0, stream>>>(x_raw, idx_raw, flags);
    cvt_idx<<<EE / 256, 256, 0, stream>>>(idx_raw, idx32, flags);
    sort_edges<<<1, 256, 0, stream>>>(idx32, sortedE, segOff);
    cvt_x<<<(NN * CC) / 256, 256, 0, stream>>>(x_raw, x_bf, x_f, flags);
    cvt_vecs<<<24, 256, 0, stream>>>(bq, bk, bv, bz, lnw, lnb, b3, b1, b2,
                                     vecF, flags);

    dim3 tb(32, 8);
    transpose_qkv<<<dim3(HCC / 32, CC / 32, 3), tb, 0, stream>>>(Wq, Wk, Wv,
                                                                 wqkvT, flags);
    transpose_cvt<<<dim3(CC / 32, HCC / 32), tb, 0, stream>>>(Wz, wzT, HCC, CC, flags);

    hipMemsetAsync(scoreF, 0, (size_t)NN * HCC * 4, stream);
    hipMemsetAsync(zF,     0, (size_t)NN * CC * 4, stream);
    hipMemsetAsync(ffnF,   0, (size_t)NN * CC * 4, stream);
    hipMemsetAsync(red,    0, 16, stream);

    // ---- projections: Q (plain), K+V merged (head=z selects weight/out) ----
    gemm_h<EPI_STORE_BIAS, false, 0><<<dim3(NN / BM, HCC / BN, 1), 256, 0, stream>>>(
        x_bf, CC, 0, wqT, CC, 0, nullptr, bqF, 0, QM, HCC, 0, CC, 0.f);
    gemm_h<EPI_STORE_BIAS, true, 1><<<dim3(EE / BM, HCC / BN, 2), 256, 0, stream>>>(
        x_bf, CC, 0, wkT, CC, (long)HCC * CC, idx32, bkF, 512,
        KM, HCC, (size_t)EE * HCC * 2, CC, 0.f);

    gather_k<<<dim3(EE / 16, 1, 4), 256, 0, stream>>>(KM, Ksort, sortedE);
    transpose_v<<<dim3(CC / 32, EE / 32, 4), tb, 0, stream>>>(VM, VT, sortedE);

    const float alpha = 0.088388347648318447f;  // 1/sqrt(128)

    if (merged) {
        // ---- attention in 3 large dispatches ----
        gemm_h<EPI_EXP, false, 1><<<dim3(NN / BM, EE / BN, 4), 256, 0, stream>>>(
            QM, CC, (long)NN * CC,
            Ksort, CC, (long)EE * CC, nullptr, vecF, 0,
            P, EE, (size_t)NN * EE * 2, CC, alpha);
        seg_norm_sorted<<<4 * NN, 1024, 0, stream>>>(P, segOff);
        gemm_h<EPI_ATOMIC, false, 2><<<dim3(NN / BM, 4, 8), 256, 0, stream>>>(
            P, EE, (long)NN * EE, VT, EE, (long)EE * CC, nullptr, vecF, 0,
            scoreF, HCC, (size_t)CC * 4, EE / 8, 0.f);
    } else {
        // ---- fallback: per query-quarter ----
        for (int qb = 0; qb < 4; qb++) {
            gemm_h<EPI_EXP, false, 1><<<dim3(QB / BM, EE / BN, 4), 256, 0, stream>>>(
                QM + (size_t)qb * QB * CC, CC, (long)NN * CC,
                Ksort, CC, (long)EE * CC, nullptr, vecF, 0,
                P, EE, (size_t)QB * EE * 2, CC, alpha);
            seg_norm_sorted<<<4 * QB, 1024, 0, stream>>>(P, segOff);
            gemm_h<EPI_ATOMIC, false, 2><<<dim3(QB / BM, 4, 8), 256, 0, stream>>>(
                P, EE, (long)QB * EE, VT, EE, (long)EE * CC, nullptr, vecF, 0,
                scoreF + (size_t)qb * QB * HCC, HCC, (size_t)CC * 4, EE / 8, 0.f);
        }
    }

    cvt_sb<<<(NN * HCC) / 256, 256, 0, stream>>>(scoreF, scoreB);

    // ---- FFN weight transposes (overlay region: attention scratch dead) ----
    transpose_cvt<<<dim3(DFF / 32, CC / 32),  tb, 0, stream>>>(W1, w1T, CC, DFF, flags);
    transpose_cvt<<<dim3(DFF / 32, DFF / 32), tb, 0, stream>>>(W2, w2T, DFF, DFF, flags);
    transpose_cvt<<<dim3(CC / 32, DFF / 32),  tb, 0, stream>>>(W3, w3T, DFF, CC, flags);

    // z = score @ Wz (split-K 8)
    gemm_h<EPI_ATOMIC, false, 0><<<dim3(NN / BM, 1, 8), 256, 0, stream>>>(
        scoreB, HCC, 0, wzT, HCC, 0, nullptr, vecF, 0,
        zF, CC, 0, HCC / 8, 0.f);
    add_bias_x_reduce<<<(NN * CC) / 256, 256, 0, stream>>>(zF, bzF, x_f, red);
    ln_fin_mid<<<(NN * CC) / 256, 256, 0, stream>>>(zF, red, lnwF, lnbF, zln,
                                                    1.f / (float)(NN * CC));

    // ---- FFN ----
    gemm_h<EPI_GELU, false, 0><<<dim3(NN / BM, DFF / BN, 1), 256, 0, stream>>>(
        zln, CC, 0, w1T, CC, 0, nullptr, b1F, 0, h1, DFF, 0, CC, 0.f);
    gemm_h<EPI_GELU, false, 0><<<dim3(NN / BM, DFF / BN, 1), 256, 0, stream>>>(
        h1, DFF, 0, w2T, DFF, 0, nullptr, b2F, 0, h2, DFF, 0, DFF, 0.f);
    gemm_h<EPI_ATOMIC, false, 0><<<dim3(NN / BM, 1, 16), 256, 0, stream>>>(
        h2, DFF, 0, w3T, DFF, 0, nullptr, vecF, 0, ffnF, CC, 0, DFF / 16, 0.f);
    add_bias_x_reduce<<<(NN * CC) / 256, 256, 0, stream>>>(ffnF, b3F, x_f, red + 2);
    ln_fin_out<<<(NN * CC) / 256, 256, 0, stream>>>(ffnF, red + 2, lnwF, lnbF,
                                                    d_out, flags,
                                                    1.f / (float)(NN * CC));
}

// Round 20
// 383.565 us; speedup vs baseline: 1.0579x; 1.0579x over previous
//
#include <hip/hip_runtime.h>

typedef unsigned short ushort_t;
typedef short short8 __attribute__((ext_vector_type(8)));
typedef float f32x4 __attribute__((ext_vector_type(4)));

// problem constants
#define NN   2048     // nodes
#define EE   8192     // edges
#define CC   128      // channels
#define HCC  512      // H*C
#define DFF  2048
#define QB   512      // query rows per quarter (fallback path)

#define BM 128
#define BN 128
#define BKK 64

enum { EPI_STORE_BIAS = 0, EPI_EXP = 1, EPI_GELU = 2, EPI_ATOMIC = 3 };

__device__ __forceinline__ float b2f(ushort_t u) {
    return __uint_as_float(((unsigned int)u) << 16);
}
__device__ __forceinline__ ushort_t f2b(float f) {
    unsigned int u = __float_as_uint(f);
    u += 0x7fffu + ((u >> 16) & 1u);   // round-to-nearest-even
    return (ushort_t)(u >> 16);
}

#define GLOAD16(gp, lp)                                                        \
    __builtin_amdgcn_global_load_lds(                                          \
        (const __attribute__((address_space(1))) unsigned int*)(gp),           \
        (__attribute__((address_space(3))) unsigned int*)(lp), 16, 0, 0)

// ---------------------------------------------------------------------------
__global__ void probe_k(const void* __restrict__ x, const void* __restrict__ idx,
                        int* __restrict__ flags)
{
    if (threadIdx.x == 0 && blockIdx.x == 0) {
        const ushort_t* xu = (const ushort_t*)x;
        float mx = 0.f;
        for (int i = 0; i < 512; i++) {
            float v = fabsf(b2f(xu[i]));
            if (v < 1e30f) mx = fmaxf(mx, v);
            else mx = 1e30f;
        }
        flags[0] = (mx > 1e4f) ? 1 : 0;
        const int* ii = (const int*)idx;
        int allz = 1;
        for (int j = 1; j < 16; j += 2)
            if (ii[j] != 0) allz = 0;
        flags[1] = allz;
    }
}

__global__ void cvt_idx(const void* __restrict__ in, int* __restrict__ out,
                        const int* __restrict__ flags)
{
    int i = blockIdx.x * 256 + threadIdx.x;
    if (i < EE)
        out[i] = flags[1] ? (int)((const long long*)in)[i] : ((const int*)in)[i];
}

// ---------------------------------------------------------------------------
// Counting sort of edges by target; emits sorted_e, seg_off, sseg.
// ---------------------------------------------------------------------------
__global__ __launch_bounds__(256)
void sort_edges(const int* __restrict__ idx, int* __restrict__ sorted_e,
                int* __restrict__ seg_off, int* __restrict__ sseg)
{
    __shared__ int hist[NN];
    __shared__ int cursor[NN];
    __shared__ float wsum[4];
    const int tid = threadIdx.x;
    for (int i = tid; i < NN; i += 256) hist[i] = 0;
    __syncthreads();
    for (int e = tid; e < EE; e += 256) atomicAdd(&hist[idx[e]], 1);
    __syncthreads();
    int s = 0;
#pragma unroll
    for (int j = 0; j < 8; j++) s += hist[tid * 8 + j];
    int lane = tid & 63, w = tid >> 6;
    int sc = s;
#pragma unroll
    for (int o = 1; o < 64; o <<= 1) {
        int t = __shfl_up(sc, o, 64);
        if (lane >= o) sc += t;
    }
    if (lane == 63) wsum[w] = (float)sc;
    __syncthreads();
    int wbase = 0;
    for (int j = 0; j < 4; j++) if (j < w) wbase += (int)wsum[j];
    int excl = wbase + sc - s;
    int run = excl;
#pragma unroll
    for (int j = 0; j < 8; j++) {
        int b = tid * 8 + j;
        cursor[b] = run;
        seg_off[b] = run;
        run += hist[b];
    }
    if (tid == 0) seg_off[NN] = EE;
    __syncthreads();
    for (int e = tid; e < EE; e += 256) {
        int t = idx[e];
        int pos = atomicAdd(&cursor[t], 1);
        sorted_e[pos] = e;
        sseg[pos] = t;
    }
}

__global__ void cvt_x(const void* __restrict__ in, ushort_t* __restrict__ xb,
                      float* __restrict__ xf, const int* __restrict__ flags)
{
    long i = (long)blockIdx.x * 256 + threadIdx.x;   // NN*CC
    float v = flags[0] ? ((const float*)in)[i] : b2f(((const ushort_t*)in)[i]);
    xf[i] = v;
    xb[i] = f2b(v);
}

__global__ void cvt_vecs(const void* bq, const void* bk, const void* bv,
                         const void* bz, const void* lnw, const void* lnb,
                         const void* b3, const void* b1, const void* b2,
                         float* __restrict__ out, const int* __restrict__ flags)
{
    int i = blockIdx.x * 256 + threadIdx.x;
    if (i >= 6144) return;
    const void* src; int o;
    if      (i < 512)  { src = bq;  o = i; }
    else if (i < 1024) { src = bk;  o = i - 512; }
    else if (i < 1536) { src = bv;  o = i - 1024; }
    else if (i < 1664) { src = bz;  o = i - 1536; }
    else if (i < 1792) { src = lnw; o = i - 1664; }
    else if (i < 1920) { src = lnb; o = i - 1792; }
    else if (i < 2048) { src = b3;  o = i - 1920; }
    else if (i < 4096) { src = b1;  o = i - 2048; }
    else               { src = b2;  o = i - 4096; }
    out[i] = flags[0] ? ((const float*)src)[o] : b2f(((const ushort_t*)src)[o]);
}

__global__ void transpose_cvt(const void* __restrict__ in, ushort_t* __restrict__ out,
                              int R, int C, const int* __restrict__ flags)
{
    __shared__ ushort_t t[32][33];
    const int f  = flags[0];
    const int bx = blockIdx.x * 32;
    const int by = blockIdx.y * 32;
    const int tx = threadIdx.x, ty = threadIdx.y;
#pragma unroll
    for (int i = 0; i < 32; i += 8) {
        long src = (long)(by + ty + i) * C + bx + tx;
        t[ty + i][tx] = f ? f2b(((const float*)in)[src]) : ((const ushort_t*)in)[src];
    }
    __syncthreads();
#pragma unroll
    for (int i = 0; i < 32; i += 8)
        out[(long)(bx + ty + i) * R + by + tx] = t[tx][ty + i];
}

__global__ void transpose_qkv(const void* q, const void* k, const void* v,
                              ushort_t* __restrict__ out, const int* __restrict__ flags)
{
    __shared__ ushort_t t[32][33];
    const void* in = blockIdx.z == 0 ? q : (blockIdx.z == 1 ? k : v);
    const int f  = flags[0];
    const int bx = blockIdx.x * 32;
    const int by = blockIdx.y * 32;
    const int tx = threadIdx.x, ty = threadIdx.y;
#pragma unroll
    for (int i = 0; i < 32; i += 8) {
        long src = (long)(by + ty + i) * HCC + bx + tx;
        t[ty + i][tx] = f ? f2b(((const float*)in)[src]) : ((const ushort_t*)in)[src];
    }
    __syncthreads();
#pragma unroll
    for (int i = 0; i < 32; i += 8)
        out[(size_t)blockIdx.z * HCC * CC + (long)(bx + ty + i) * CC + by + tx]
            = t[tx][ty + i];
}

__global__ __launch_bounds__(256)
void gather_k(const ushort_t* __restrict__ KM, ushort_t* __restrict__ Ksort,
              const int* __restrict__ sorted_e)
{
    const size_t hb = (size_t)blockIdx.z * EE * CC;
    const int j  = blockIdx.x * 16 + (threadIdx.x >> 4);
    const int l8 = (threadIdx.x & 15) * 8;
    const int e  = sorted_e[j];
    *(short8*)(Ksort + hb + (size_t)j * CC + l8) =
        *(const short8*)(KM + hb + (size_t)e * CC + l8);
}

__global__ void transpose_v(const ushort_t* __restrict__ VM, ushort_t* __restrict__ VT,
                            const int* __restrict__ sorted_e)
{
    __shared__ ushort_t t[32][33];
    const ushort_t* in = VM + (size_t)blockIdx.z * EE * CC;
    ushort_t* out      = VT + (size_t)blockIdx.z * EE * CC;
    const int bx = blockIdx.x * 32;
    const int by = blockIdx.y * 32;
    const int tx = threadIdx.x, ty = threadIdx.y;
#pragma unroll
    for (int i = 0; i < 32; i += 8) {
        const long rg = sorted_e[by + ty + i];
        t[ty + i][tx] = in[rg * CC + bx + tx];
    }
    __syncthreads();
#pragma unroll
    for (int i = 0; i < 32; i += 8)
        out[(long)(bx + ty + i) * EE + by + tx] = t[tx][ty + i];
}

// ---------------------------------------------------------------------------
// Unified NT GEMM. MODE 0: bz = split-K. MODE 1: bz = head. MODE 2: by =
// head, bz = split-K. Strides aHS/bHS/biasHS in elements, cHS in BYTES.
// T2 LDS XOR-swizzle on staging (r11: conflicts 6.29M -> 0).
// T1 XCD bijective block swizzle (r12: FETCH -45%).
// r13: non-atomic epilogues LDS-stage the C tile, coalesced short8 stores.
// r17: 2-phase double-buffered prefetch (pays on large-kchunk dispatches).
// ---------------------------------------------------------------------------
template <int EPI, bool GATHER, int MODE>
__global__ __launch_bounds__(256, 2)
void gemm_h(const ushort_t* __restrict__ A, long lda, long aHS,
            const ushort_t* __restrict__ B, long ldb, long bHS,
            const int* __restrict__ gidx,
            const float* __restrict__ bias, long biasHS,
            void* __restrict__ Cp, long ldc, long cHS,
            int kchunk, float alpha)
{
    constexpr int TSZ = BM * BKK + BN * BKK;          // 16384 elems = 32 KB
    __shared__ __align__(16) ushort_t smem[2 * TSZ];  // double buffer, 64 KB

    const int tid  = threadIdx.x;
    const int lane = tid & 63;
    const int wave = tid >> 6;

    // ---- T1: bijective XCD swizzle over the flattened grid ----
    const int gx = gridDim.x, gy = gridDim.y;
    const int nwg = gx * gy * gridDim.z;
    const int bid = blockIdx.x + gx * (blockIdx.y + gy * blockIdx.z);
    const int q8 = nwg >> 3, r8 = nwg & 7;
    const int xcd = bid & 7, slot = bid >> 3;
    const int nb = (xcd < r8) ? (xcd * (q8 + 1) + slot) : (r8 + xcd * q8 + slot);
    const int bxi = nb % gx;
    const int tq  = nb / gx;
    const int byi = tq % gy;
    const int bzi = tq / gy;

    const long bm = (long)bxi * BM;

    long bn; int head, k0;
    if (MODE == 1)      { head = bzi; k0 = 0;               bn = (long)byi * BN; }
    else if (MODE == 2) { head = byi; k0 = bzi * kchunk;    bn = 0; }
    else                { head = 0;   k0 = bzi * kchunk;    bn = (long)byi * BN; }
    const int k1 = k0 + kchunk;

    A += (size_t)head * aHS;
    B += (size_t)head * bHS;
    const float* bp = bias + (size_t)head * biasHS;
    Cp = (void*)((char*)Cp + (size_t)head * cHS);

    const f32x4 fzero = {0.f, 0.f, 0.f, 0.f};
    f32x4 acc[4][4];
#pragma unroll
    for (int i = 0; i < 4; i++)
#pragma unroll
        for (int j = 0; j < 4; j++) acc[i][j] = fzero;

    const int arow = tid >> 3;          // 0..31
    const int acol = (((tid & 7) ^ (arow & 7)) * 8);   // T2 source swizzle

    const ushort_t* ap[4];
    const ushort_t* bpt[4];
#pragma unroll
    for (int i = 0; i < 4; i++) {
        long r  = bm + arow + i * 32;     // (arow+32i)&7 == arow&7
        long gr = GATHER ? (long)gidx[r] : r;
        ap[i]  = A + gr * lda + acol;
        bpt[i] = B + (bn + arow + i * 32) * ldb + acol;
    }
    const int t8  = tid * 8;
    const int wr  = (wave >> 1) * 64;
    const int wc  = (wave & 1) * 64;
    const int ra  = lane & 15;
    const int kgi = lane >> 4;            // 0..3 k-group
    const int r7  = lane & 7;             // row&7 of the fragment row

    // ---- prologue: stage first K-tile into buffer 0 ----
    {
        ushort_t* As0 = smem;
        ushort_t* Bs0 = smem + BM * BKK;
#pragma unroll
        for (int i = 0; i < 4; i++) GLOAD16(ap[i] + k0, &As0[t8 + i * 2048]);
#pragma unroll
        for (int i = 0; i < 4; i++) GLOAD16(bpt[i] + k0, &Bs0[t8 + i * 2048]);
    }
    asm volatile("s_waitcnt vmcnt(0)" ::: "memory");
    __builtin_amdgcn_s_barrier();

    int cur = 0;
    for (int kt = k0; kt < k1; kt += BKK) {
        // issue NEXT tile's loads first — in flight during this compute
        if (kt + BKK < k1) {
            ushort_t* Asn = smem + (cur ^ 1) * TSZ;
            ushort_t* Bsn = Asn + BM * BKK;
#pragma unroll
            for (int i = 0; i < 4; i++)
                GLOAD16(ap[i] + kt + BKK, &Asn[t8 + i * 2048]);
#pragma unroll
            for (int i = 0; i < 4; i++)
                GLOAD16(bpt[i] + kt + BKK, &Bsn[t8 + i * 2048]);
        }
        // compute current buffer
        const ushort_t* Asc = smem + cur * TSZ;
        const ushort_t* Bsc = Asc + BM * BKK;
#pragma unroll
        for (int ks = 0; ks < 2; ks++) {
            const int cswz = (((ks * 4 + kgi) ^ r7) * 8);   // swizzled chunk
            short8 af[4], bfr[4];
#pragma unroll
            for (int mi = 0; mi < 4; mi++)
                af[mi] = *(const short8*)&Asc[(wr + mi * 16 + ra) * BKK + cswz];
#pragma unroll
            for (int ni = 0; ni < 4; ni++)
                bfr[ni] = *(const short8*)&Bsc[(wc + ni * 16 + ra) * BKK + cswz];
#pragma unroll
            for (int mi = 0; mi < 4; mi++)
#pragma unroll
                for (int ni = 0; ni < 4; ni++)
                    acc[mi][ni] = __builtin_amdgcn_mfma_f32_16x16x32_bf16(
                        af[mi], bfr[ni], acc[mi][ni], 0, 0, 0);
        }
        asm volatile("s_waitcnt vmcnt(0)" ::: "memory");
        __builtin_amdgcn_s_barrier();
        cur ^= 1;
    }

    if (EPI == EPI_ATOMIC) {
#pragma unroll
        for (int mi = 0; mi < 4; mi++) {
#pragma unroll
            for (int ni = 0; ni < 4; ni++) {
                const long row0 = bm + wr + mi * 16 + (lane >> 4) * 4;
                const long col  = bn + wc + ni * 16 + ra;
#pragma unroll
                for (int r = 0; r < 4; r++)
                    unsafeAtomicAdd(&((float*)Cp)[(row0 + r) * ldc + col],
                                    acc[mi][ni][r]);
            }
        }
    } else {
        // ---- LDS-staged coalesced C write (reuses smem as 128x128 tile) ----
        ushort_t* Cs = smem;
#pragma unroll
        for (int mi = 0; mi < 4; mi++) {
#pragma unroll
            for (int ni = 0; ni < 4; ni++) {
                const int crow0 = wr + mi * 16 + (lane >> 4) * 4;
                const int ccol  = wc + ni * 16 + ra;
#pragma unroll
                for (int r = 0; r < 4; r++) {
                    float v = acc[mi][ni][r];
                    if (EPI == EPI_STORE_BIAS) {
                        v += bp[bn + ccol];
                    } else if (EPI == EPI_EXP) {
                        v = __expf(v * alpha);
                    } else { // EPI_GELU
                        v += bp[bn + ccol];
                        v = 0.5f * v * (1.f + erff(v * 0.70710678118654752f));
                    }
                    const int crow = crow0 + r;
                    Cs[crow * BN + (ccol ^ (((crow & 7) << 3)))] = f2b(v);
                }
            }
        }
        __syncthreads();
#pragma unroll
        for (int it = 0; it < 8; it++) {
            const int idx = it * 2048 + tid * 8;
            const int row = idx >> 7;
            const int col = idx & 127;
            *(short8*)((ushort_t*)Cp + (bm + row) * ldc + bn + col) =
                *(const short8*)&Cs[row * BN + (col ^ ((row & 7) << 3))];
        }
    }
}

// ---------------------------------------------------------------------------
// Segmented softmax normalize on sorted-column P.
// r20: PARALLEL PREFIX SUM replaces the serial segment walk. r19 proved the
// divergent walk is the conflict source (conflicts scaled with walk ops:
// 12.07M read-walk -> 19.11M read+write-walk). Now: per-thread register
// prefix of its 8 values, wave shfl scan + cross-wave scan of totals, write
// inclusive prefix to rowf (same 2-way-free pattern as load), D from prefix
// differences at segment boundaries (3 scattered reads/thread), multiply
// the register-held values by D[sseg[e]] (measured-cheap gather) and store.
// Numerics: row total ~9e3 -> prefix-difference error ~1e-3 absolute on
// segment sums >=0.05 — ~0.03% relative, well within tolerance headroom.
// ---------------------------------------------------------------------------
#define PH(e) ((e) + ((e) >> 6))
__global__ __launch_bounds__(1024)
void seg_norm_sorted(ushort_t* __restrict__ P, const int* __restrict__ seg_off,
                     const int* __restrict__ sseg)
{
    __shared__ float rowf[EE + EE / 64];   // 33.3 KB padded (prefix storage)
    __shared__ float D[NN];                //  8 KB
    __shared__ float wpart[16];
    ushort_t* row = P + (long)blockIdx.x * EE;
    const int tid  = threadIdx.x;
    const int lane = tid & 63;
    const int wid  = tid >> 6;
    const int e    = tid * 8;

    // load own 8 values (kept in registers), local inclusive prefix
    short8 v = *(const short8*)(row + e);
    float lp[8];
    {
        float s = 0.f;
#pragma unroll
        for (int j = 0; j < 8; j++) { s += b2f((ushort_t)v[j]); lp[j] = s; }
    }
    const float tot = lp[7];

    // wave-inclusive scan of thread totals
    float sc = tot;
#pragma unroll
    for (int o = 1; o < 64; o <<= 1) {
        float t = __shfl_up(sc, o, 64);
        if (lane >= o) sc += t;
    }
    if (lane == 63) wpart[wid] = sc;
    __syncthreads();
    float base = sc - tot;                 // exclusive within wave
    for (int w = 0; w < wid; w++) base += wpart[w];   // broadcast reads

    // inclusive prefix of the whole row into rowf
#pragma unroll
    for (int j = 0; j < 8; j++) rowf[PH(e + j)] = base + lp[j];
    __syncthreads();

    // segment inverse sums from prefix differences (2 segments per thread)
    {
        const int t2 = tid * 2;
        const int s0 = seg_off[t2], s1 = seg_off[t2 + 1], s2 = seg_off[t2 + 2];
        const float p0 = s0 ? rowf[PH(s0 - 1)] : 0.f;
        const float p1 = s1 ? rowf[PH(s1 - 1)] : 0.f;
        const float p2 = s2 ? rowf[PH(s2 - 1)] : 0.f;
        D[t2]     = 1.f / (p1 - p0 + 1e-16f);
        D[t2 + 1] = 1.f / (p2 - p1 + 1e-16f);
    }
    __syncthreads();

    // normalize own register values, coalesced store
    {
        short8 o;
#pragma unroll
        for (int j = 0; j < 8; j++)
            o[j] = (short)f2b(b2f((ushort_t)v[j]) * D[sseg[e + j]]);
        *(short8*)(row + e) = o;
    }
}

// scoreF [NN,HCC] f32 -> bf16
__global__ void cvt_sb(const float* __restrict__ in, ushort_t* __restrict__ out)
{
    long i = (long)blockIdx.x * 256 + threadIdx.x;
    out[i] = f2b(in[i]);
}

__global__ __launch_bounds__(256)
void add_bias_x_reduce(float* __restrict__ u, const float* __restrict__ bias,
                       const float* __restrict__ x, float* __restrict__ red)
{
    long i = (long)blockIdx.x * 256 + threadIdx.x;
    float v = u[i] + bias[i & (CC - 1)] + x[i];
    u[i] = v;
    float s = v, s2 = v * v;
#pragma unroll
    for (int o = 32; o > 0; o >>= 1) {
        s  += __shfl_down(s, o, 64);
        s2 += __shfl_down(s2, o, 64);
    }
    __shared__ float ps[4], ps2[4];
    int w = threadIdx.x >> 6;
    if ((threadIdx.x & 63) == 0) { ps[w] = s; ps2[w] = s2; }
    __syncthreads();
    if (threadIdx.x == 0) {
        float a = 0.f, b = 0.f;
#pragma unroll
        for (int j = 0; j < 4; j++) { a += ps[j]; b += ps2[j]; }
        unsafeAtomicAdd(&red[0], a);
        unsafeAtomicAdd(&red[1], b);
    }
}

__global__ void ln_fin_mid(const float* __restrict__ u, const float* __restrict__ red,
                           const float* __restrict__ w, const float* __restrict__ b,
                           ushort_t* __restrict__ out, float invn)
{
    long i = (long)blockIdx.x * 256 + threadIdx.x;
    float mean = red[0] * invn;
    float var  = red[1] * invn - mean * mean;
    float rs   = rsqrtf(var + 1e-5f);
    int c = (int)(i & (CC - 1));
    out[i] = f2b((u[i] - mean) * rs * w[c] + b[c]);
}

__global__ void ln_fin_out(const float* __restrict__ u, const float* __restrict__ red,
                           const float* __restrict__ w, const float* __restrict__ b,
                           void* __restrict__ out, const int* __restrict__ flags,
                           float invn)
{
    long i = (long)blockIdx.x * 256 + threadIdx.x;
    float mean = red[0] * invn;
    float var  = red[1] * invn - mean * mean;
    float rs   = rsqrtf(var + 1e-5f);
    int c = (int)(i & (CC - 1));
    float v = (u[i] - mean) * rs * w[c] + b[c];
    if (flags[0]) ((float*)out)[i] = v;
    else          ((ushort_t*)out)[i] = f2b(v);
}

// ---------------------------------------------------------------------------
extern "C" void kernel_launch(void* const* d_in, const int* in_sizes, int n_in,
                              void* d_out, int out_size, void* d_ws, size_t ws_size,
                              hipStream_t stream)
{
    const void* x_raw   = d_in[0];
    const void* idx_raw = d_in[1];
    const void* Wq = d_in[2];  const void* bq = d_in[3];
    const void* Wk = d_in[4];  const void* bk = d_in[5];
    const void* Wv = d_in[6];  const void* bv = d_in[7];
    const void* Wz = d_in[8];  const void* bz = d_in[9];
    const void* lnw = d_in[10]; const void* lnb = d_in[11];
    const void* W1 = d_in[12]; const void* b1 = d_in[13];
    const void* W2 = d_in[14]; const void* b2 = d_in[15];
    const void* W3 = d_in[16]; const void* b3 = d_in[17];

    char* ws = (char*)d_ws;
    size_t off = 0;
    auto carve = [&](size_t bytes) -> char* {
        char* p = ws + off;
        off += (bytes + 255) & ~(size_t)255;
        return p;
    };

    // ---- persistent region (~6 MB) ----
    int*      flags  = (int*)     carve(256);
    int*      idx32  = (int*)     carve((size_t)EE * 4);
    int*      sortedE= (int*)     carve((size_t)EE * 4);
    int*      segOff = (int*)     carve((size_t)(NN + 1) * 4);
    int*      ssegB  = (int*)     carve((size_t)EE * 4);
    ushort_t* x_bf  = (ushort_t*)carve((size_t)NN * CC * 2);
    float*    x_f   = (float*)   carve((size_t)NN * CC * 4);
    float*    vecF  = (float*)   carve(6144 * 4);
    float*    bqF  = vecF;        float* bkF  = vecF + 512;
    float*    bzF  = vecF + 1536;
    float*    lnwF = vecF + 1664; float* lnbF = vecF + 1792;
    float*    b3F  = vecF + 1920; float* b1F  = vecF + 2048;
    float*    b2F  = vecF + 4096;
    ushort_t* wqkvT = (ushort_t*)carve((size_t)3 * HCC * CC * 2);
    ushort_t* wqT = wqkvT;
    ushort_t* wkT = wqkvT + (size_t)HCC * CC;   // wvT adjacent (bHS)
    ushort_t* wzT   = (ushort_t*)carve((size_t)CC * HCC * 2);
    ushort_t* scoreB= (ushort_t*)carve((size_t)NN * HCC * 2);
    float*    zF    = (float*)   carve((size_t)NN * CC * 4);
    ushort_t* zln   = (ushort_t*)carve((size_t)NN * CC * 2);
    float*    ffnF  = (float*)   carve((size_t)NN * CC * 4);
    float*    red   = (float*)   carve(256);

    // ---- attention scratch, overlaid by FFN scratch ----
    size_t scratch0 = off;
    ushort_t* QM    = (ushort_t*)carve((size_t)NN * HCC * 2);       // 2 MB
    ushort_t* KVM   = (ushort_t*)carve((size_t)2 * EE * HCC * 2);   // 16 MB (KM|VM)
    ushort_t* KM = KVM;
    ushort_t* VM = KVM + (size_t)EE * HCC;
    ushort_t* Ksort = (ushort_t*)carve((size_t)EE * HCC * 2);       // 8 MB
    ushort_t* VT    = (ushort_t*)carve((size_t)EE * HCC * 2);       // 8 MB
    float*    scoreF= (float*)   carve((size_t)NN * HCC * 4);       // 4 MB
    size_t pOff = off;
    // merged path: full P [4 heads][2048 rows][8192] = 128 MB
    off = pOff;
    carve((size_t)4 * NN * EE * 2);
    size_t total_attn_full = off;
    // quartered fallback: P [4 heads][512 rows][8192] = 32 MB
    size_t total_attn_quart = pOff + (((size_t)4 * QB * EE * 2 + 255) & ~(size_t)255);
    ushort_t* P = (ushort_t*)(ws + pOff);
    // FFN overlay
    off = scratch0;
    ushort_t* w1T = (ushort_t*)carve((size_t)DFF * CC * 2);
    ushort_t* w2T = (ushort_t*)carve((size_t)DFF * DFF * 2);
    ushort_t* w3T = (ushort_t*)carve((size_t)CC * DFF * 2);
    ushort_t* h1  = (ushort_t*)carve((size_t)NN * DFF * 2);
    ushort_t* h2  = (ushort_t*)carve((size_t)NN * DFF * 2);
    size_t total_ffn = off;

    const bool merged = ws_size >= (total_attn_full > total_ffn ? total_attn_full
                                                                : total_ffn);
    size_t required_attn = merged ? total_attn_full : total_attn_quart;
    size_t required = required_attn > total_ffn ? required_attn : total_ffn;
    if (ws_size < required) return;   // diagnostic: absmax ~5 => ws too small

    // ---- canonicalization + edge sort ----
    probe_k<<<1, 64, 0, stream>>>(x_raw, idx_raw, flags);
    cvt_idx<<<EE / 256, 256, 0, stream>>>(idx_raw, idx32, flags);
    sort_edges<<<1, 256, 0, stream>>>(idx32, sortedE, segOff, ssegB);
    cvt_x<<<(NN * CC) / 256, 256, 0, stream>>>(x_raw, x_bf, x_f, flags);
    cvt_vecs<<<24, 256, 0, stream>>>(bq, bk, bv, bz, lnw, lnb, b3, b1, b2,
                                     vecF, flags);

    dim3 tb(32, 8);
    transpose_qkv<<<dim3(HCC / 32, CC / 32, 3), tb, 0, stream>>>(Wq, Wk, Wv,
                                                                 wqkvT, flags);
    transpose_cvt<<<dim3(CC / 32, HCC / 32), tb, 0, stream>>>(Wz, wzT, HCC, CC, flags);

    hipMemsetAsync(scoreF, 0, (size_t)NN * HCC * 4, stream);
    hipMemsetAsync(zF,     0, (size_t)NN * CC * 4, stream);
    hipMemsetAsync(ffnF,   0, (size_t)NN * CC * 4, stream);
    hipMemsetAsync(red,    0, 16, stream);

    // ---- projections: Q (plain), K+V merged (head=z selects weight/out) ----
    gemm_h<EPI_STORE_BIAS, false, 0><<<dim3(NN / BM, HCC / BN, 1), 256, 0, stream>>>(
        x_bf, CC, 0, wqT, CC, 0, nullptr, bqF, 0, QM, HCC, 0, CC, 0.f);
    gemm_h<EPI_STORE_BIAS, true, 1><<<dim3(EE / BM, HCC / BN, 2), 256, 0, stream>>>(
        x_bf, CC, 0, wkT, CC, (long)HCC * CC, idx32, bkF, 512,
        KM, HCC, (size_t)EE * HCC * 2, CC, 0.f);

    gather_k<<<dim3(EE / 16, 1, 4), 256, 0, stream>>>(KM, Ksort, sortedE);
    transpose_v<<<dim3(CC / 32, EE / 32, 4), tb, 0, stream>>>(VM, VT, sortedE);

    const float alpha = 0.088388347648318447f;  // 1/sqrt(128)

    if (merged) {
        // ---- attention in 3 large dispatches ----
        gemm_h<EPI_EXP, false, 1><<<dim3(NN / BM, EE / BN, 4), 256, 0, stream>>>(
            QM, CC, (long)NN * CC,
            Ksort, CC, (long)EE * CC, nullptr, vecF, 0,
            P, EE, (size_t)NN * EE * 2, CC, alpha);
        seg_norm_sorted<<<4 * NN, 1024, 0, stream>>>(P, segOff, ssegB);
        gemm_h<EPI_ATOMIC, false, 2><<<dim3(NN / BM, 4, 8), 256, 0, stream>>>(
            P, EE, (long)NN * EE, VT, EE, (long)EE * CC, nullptr, vecF, 0,
            scoreF, HCC, (size_t)CC * 4, EE / 8, 0.f);
    } else {
        // ---- fallback: per query-quarter ----
        for (int qb = 0; qb < 4; qb++) {
            gemm_h<EPI_EXP, false, 1><<<dim3(QB / BM, EE / BN, 4), 256, 0, stream>>>(
                QM + (size_t)qb * QB * CC, CC, (long)NN * CC,
                Ksort, CC, (long)EE * CC, nullptr, vecF, 0,
                P, EE, (size_t)QB * EE * 2, CC, alpha);
            seg_norm_sorted<<<4 * QB, 1024, 0, stream>>>(P, segOff, ssegB);
            gemm_h<EPI_ATOMIC, false, 2><<<dim3(QB / BM, 4, 8), 256, 0, stream>>>(
                P, EE, (long)QB * EE, VT, EE, (long)EE * CC, nullptr, vecF, 0,
                scoreF + (size_t)qb * QB * HCC, HCC, (size_t)CC * 4, EE / 8, 0.f);
        }
    }

    cvt_sb<<<(NN * HCC) / 256, 256, 0, stream>>>(scoreF, scoreB);

    // ---- FFN weight transposes (overlay region: attention scratch dead) ----
    transpose_cvt<<<dim3(DFF / 32, CC / 32),  tb, 0, stream>>>(W1, w1T, CC, DFF, flags);
    transpose_cvt<<<dim3(DFF / 32, DFF / 32), tb, 0, stream>>>(W2, w2T, DFF, DFF, flags);
    transpose_cvt<<<dim3(CC / 32, DFF / 32),  tb, 0, stream>>>(W3, w3T, DFF, CC, flags);

    // z = score @ Wz (split-K 8)
    gemm_h<EPI_ATOMIC, false, 0><<<dim3(NN / BM, 1, 8), 256, 0, stream>>>(
        scoreB, HCC, 0, wzT, HCC, 0, nullptr, vecF, 0,
        zF, CC, 0, HCC / 8, 0.f);
    add_bias_x_reduce<<<(NN * CC) / 256, 256, 0, stream>>>(zF, bzF, x_f, red);
    ln_fin_mid<<<(NN * CC) / 256, 256, 0, stream>>>(zF, red, lnwF, lnbF, zln,
                                                    1.f / (float)(NN * CC));

    // ---- FFN ----
    gemm_h<EPI_GELU, false, 0><<<dim3(NN / BM, DFF / BN, 1), 256, 0, stream>>>(
        zln, CC, 0, w1T, CC, 0, nullptr, b1F, 0, h1, DFF, 0, CC, 0.f);
    gemm_h<EPI_GELU, false, 0><<<dim3(NN / BM, DFF / BN, 1), 256, 0, stream>>>(
        h1, DFF, 0, w2T, DFF, 0, nullptr, b2F, 0, h2, DFF, 0, DFF, 0.f);
    gemm_h<EPI_ATOMIC, false, 0><<<dim3(NN / BM, 1, 16), 256, 0, stream>>>(
        h2, DFF, 0, w3T, DFF, 0, nullptr, vecF, 0, ffnF, CC, 0, DFF / 16, 0.f);
    add_bias_x_reduce<<<(NN * CC) / 256, 256, 0, stream>>>(ffnF, b3F, x_f, red + 2);
    ln_fin_out<<<(NN * CC) / 256, 256, 0, stream>>>(ffnF, red + 2, lnwF, lnbF,
                                                    d_out, flags,
                                                    1.f / (float)(NN * CC));
}